// Round 5
// baseline (386.444 us; speedup 1.0000x reference)
//
#include <hip/hip_runtime.h>

// Problem constants: B=2, S=2048, D=2048, H=16, DH=128
#define B_  2
#define S_  2048
#define D_  2048
#define H_  16
#define DH_ 128
#define NQKV 6144              // Q|K|V concatenated column dim

typedef __bf16 bf16;
typedef __bf16 bf16x2 __attribute__((ext_vector_type(2)));
typedef __bf16 bf16x4 __attribute__((ext_vector_type(4)));
typedef __bf16 bf16x8 __attribute__((ext_vector_type(8)));
typedef float  f32x4  __attribute__((ext_vector_type(4)));

// 2^x and log2(x) via the raw ISA ops (v_exp_f32 / v_log_f32).
#define EXP2F(x) __builtin_amdgcn_exp2f(x)
#define LOG2F(x) __builtin_amdgcn_logf(x)

// DH^-0.5 * log2(e): fold softmax scale AND the exp->exp2 conversion into Q.
static constexpr float kQScale = 0.08838834764831845f * 1.4426950408889634f;

__device__ __forceinline__ void async16(const void* g, void* l) {
  __builtin_amdgcn_global_load_lds(
      (const __attribute__((address_space(1))) void*)g,
      (__attribute__((address_space(3))) void*)l, 16, 0, 0);
}

// ---------------------------------------------------------------------------
// Single fp32 -> bf16 conversion kernel for all 5 tensors (block-uniform
// region select; merging 5 dispatches -> 1 to cut launch overhead).
// Regions (blocks of 1024 elems): x:8192 | Wq:4096 | Wk:4096 | Wv:4096 | Wo:4096
__global__ void cvt_all(const float* __restrict__ x,  const float* __restrict__ wq,
                        const float* __restrict__ wk, const float* __restrict__ wv,
                        const float* __restrict__ wo,
                        bf16* __restrict__ xb, bf16* __restrict__ wqkv,
                        bf16* __restrict__ wob) {
  int bid = blockIdx.x;
  const float* s; bf16* d; int base;
  if (bid < 8192)        { s = x;  d = xb;             base = bid; }
  else if (bid < 12288)  { s = wq; d = wqkv;           base = bid - 8192; }
  else if (bid < 16384)  { s = wk; d = wqkv + 4194304; base = bid - 12288; }
  else if (bid < 20480)  { s = wv; d = wqkv + 8388608; base = bid - 16384; }
  else                   { s = wo; d = wob;            base = bid - 20480; }
  int i = (base * 256 + threadIdx.x) * 4;
  float4 v = *(const float4*)(s + i);
  bf16x4 o = {(bf16)v.x, (bf16)v.y, (bf16)v.z, (bf16)v.w};
  *(bf16x4*)(d + i) = o;
}

// ---------------------------------------------------------------------------
// GEMM1 (m97 geometry: BK=32, 16 KB LDS, same 2-barrier schedule): qkv =
// x(4096x2048) * Wqkv^T (6144x2048), RoPE fused for the Q,K column regions
// (f32 via lane-pair shfl), Q scaled by kQScale. Output row-major 4096x6144.
// Round-4 history: BK=64/32KB measured 727 TF; m97 evidence (874-912 TF, same
// schedule, 16 KB) motivates BK=32. Conflicts left as-is (regime-gate: T2
// null at 2-phase). 8-phase rewrites r2/r3 both regressed — do not revisit.
__global__ __launch_bounds__(256, 2) void gemm_qkv(
    const bf16* __restrict__ A, const bf16* __restrict__ Bm,
    const float* __restrict__ rc, const float* __restrict__ rs,
    bf16* __restrict__ C) {
  __shared__ alignas(16) bf16 As[128 * 32];   // 8 KB
  __shared__ alignas(16) bf16 Bs[128 * 32];   // 8 KB
  const int tid = threadIdx.x;
  const int lane = tid & 63;
  const int wv = tid >> 6;
  const int quad = lane >> 4, c16 = lane & 15;
  const int wm = (wv >> 1) * 64, wn = (wv & 1) * 64;
  const int m0 = blockIdx.y * 128, n0 = blockIdx.x * 128;

  const bf16* ag = A  + (size_t)(m0 + (tid >> 2)) * D_ + (tid & 3) * 8;
  const bf16* bg = Bm + (size_t)(n0 + (tid >> 2)) * D_ + (tid & 3) * 8;
  char* asl = (char*)As + tid * 16;
  char* bsl = (char*)Bs + tid * 16;

  f32x4 acc[4][4] = {};
  for (int k0 = 0; k0 < D_; k0 += 32) {
    __syncthreads();
    async16(ag + k0,            asl);
    async16(ag + k0 + 64 * D_,  asl + 4096);
    async16(bg + k0,            bsl);
    async16(bg + k0 + 64 * D_,  bsl + 4096);
    __syncthreads();
    bf16x8 af[4], bfr[4];
#pragma unroll
    for (int i = 0; i < 4; ++i)
      af[i] = *(const bf16x8*)(As + (wm + i * 16 + c16) * 32 + quad * 8);
#pragma unroll
    for (int j = 0; j < 4; ++j)
      bfr[j] = *(const bf16x8*)(Bs + (wn + j * 16 + c16) * 32 + quad * 8);
#pragma unroll
    for (int i = 0; i < 4; ++i)
#pragma unroll
      for (int j = 0; j < 4; ++j)
        acc[i][j] = __builtin_amdgcn_mfma_f32_16x16x32_bf16(af[i], bfr[j], acc[i][j], 0, 0, 0);
  }

  // ---- epilogue (n0 block-uniform: Q / K get RoPE, V passes through) ----
  if (n0 < 4096) {
    const float sc = (n0 < 2048) ? kQScale : 1.0f;
#pragma unroll
    for (int i = 0; i < 4; ++i) {
      const int gmi = m0 + wm + i * 16 + quad * 4;
#pragma unroll
      for (int j = 0; j < 4; ++j) {
        const int gn = n0 + wn + j * 16 + c16;
        const int d = gn & 127;
#pragma unroll
        for (int r = 0; r < 4; ++r) {
          float v = acc[i][j][r];
          float p = __shfl_xor(v, 1);          // partner (odd<->even d)
          const int gm = gmi + r;
          const int s = gm & 2047;
          const int si = s * 64 + (d >> 1);
          float c = rc[si], sn = rs[si];
          float re = (v * c - p * sn) * sc;    // valid on even lanes
          float im = (v * sn + p * c) * sc;
          if (!(lane & 1)) {
            bf16x2 o = {(bf16)re, (bf16)im};
            *(bf16x2*)(C + (size_t)gm * NQKV + gn) = o;
          }
        }
      }
    }
  } else {
#pragma unroll
    for (int i = 0; i < 4; ++i) {
      const int gmi = m0 + wm + i * 16 + quad * 4;
#pragma unroll
      for (int j = 0; j < 4; ++j) {
        const int gn = n0 + wn + j * 16 + c16;
#pragma unroll
        for (int r = 0; r < 4; ++r) {
          float v = acc[i][j][r];
          float p = __shfl_xor(v, 1);
          if (!(lane & 1)) {
            bf16x2 o = {(bf16)v, (bf16)p};
            *(bf16x2*)(C + (size_t)(gmi + r) * NQKV + gn) = o;
          }
        }
      }
    }
  }
}

// ---------------------------------------------------------------------------
// Fused per-(b,h) score + weight + V-scale kernel (v3):
//   lse2[s] = log2 sum_k 2^(q'_s . k_k), diag2[s] = q'_s . k_s  (LDS only)
//   t[b,s,h*128+d] = 2^(diag2-lse2) * V[b,s,h*128+d]
// v3 changes vs round-0 v1 (same 2-barrier schedule, same diag/lse/V logic):
//  - Q-HOIST: wave's Q fragments are n0-loop-invariant -> 8x16B/lane direct
//    from global once (L3-resident); Qs LDS deleted (staging + 8 reads/iter).
//  - K tile [128][128] bf16, 256-B rows, XOR-swizzled (chunk ^= row&7).
//    Stage: linear LDS dest, pre-swizzled global source col; read: same XOR.
//    Per quarter-wave, 16 lanes spread across 8 bank-groups x 2 = conflict-
//    free (m136: 2-way free). v1 pattern was 8-way (64-B rows).
__global__ __launch_bounds__(256, 2) void score_wv(
    const bf16* __restrict__ qkv, bf16* __restrict__ t) {
  __shared__ alignas(16) bf16 Ks[128 * 128];  // 32 KB, swizzled 256-B rows
  __shared__ float diagL[128];
  __shared__ float lseL[128];
  const int tid = threadIdx.x;
  const int lane = tid & 63, wv = tid >> 6;
  const int quad = lane >> 4, c16 = lane & 15;
  const int wm = wv * 32;                 // each wave owns 32 distinct Q rows
  const int bh = blockIdx.y;
  const int b = bh >> 4, h = bh & 15;
  const int m0 = blockIdx.x * 128;

  // ---- Q-hoist: fragments direct global->VGPR (32 VGPRs), once ----
  bf16x8 qf[2][4];                        // [i][kt]
  {
    const bf16* qbase = qkv + (size_t)(b * 2048 + m0 + wm + c16) * NQKV
                      + h * 128 + quad * 8;
#pragma unroll
    for (int i = 0; i < 2; ++i)
#pragma unroll
      for (int kt = 0; kt < 4; ++kt)
        qf[i][kt] = *(const bf16x8*)(qbase + (size_t)(i * 16) * NQKV + kt * 32);
  }

  // ---- K staging map: thread tid -> row i*16+(tid>>4), chunk tid&15 (linear
  //      dest tid*16 + i*4096); source chunk pre-swizzled by row&7 ----
  const int srow = tid >> 4;                    // 0..15
  const int schunk = (tid & 15) ^ (srow & 7);   // involution partner
  const bf16* kg = qkv + (size_t)(b * 2048 + srow) * NQKV
                 + 2048 + h * 128 + schunk * 8;
  char* kl = (char*)Ks + tid * 16;

  float sums[8] = {0.f, 0.f, 0.f, 0.f, 0.f, 0.f, 0.f, 0.f};

  for (int n0 = 0; n0 < S_; n0 += 128) {
    __syncthreads();                            // prior iter's Ks reads done
#pragma unroll
    for (int i = 0; i < 8; ++i)
      async16(kg + (size_t)(n0 + i * 16) * NQKV, kl + i * 4096);
    __syncthreads();                            // K chunk landed
    f32x4 acc[2][8] = {};
#pragma unroll
    for (int kt = 0; kt < 4; ++kt) {
#pragma unroll
      for (int j = 0; j < 8; ++j) {
        // row j*16+c16, chunk (kt*4+quad) ^ (c16&7)  [row&7 == c16&7]
        bf16x8 bb = *(const bf16x8*)((const char*)Ks + (j * 16 + c16) * 256
                        + ((((kt * 4 + quad) ^ (c16 & 7))) << 4));
#pragma unroll
        for (int i = 0; i < 2; ++i)
          acc[i][j] = __builtin_amdgcn_mfma_f32_16x16x32_bf16(qf[i][kt], bb, acc[i][j], 0, 0, 0);
      }
    }
    // Diagonal tile only; compile-time acc indices, wave-uniform j guard.
    if (n0 == m0) {
#pragma unroll
      for (int i = 0; i < 2; ++i)
#pragma unroll
        for (int j = 0; j < 8; ++j)
          if (j == 2 * wv + i) {
#pragma unroll
            for (int r = 0; r < 4; ++r)
              if (c16 == quad * 4 + r)
                diagL[wm + i * 16 + quad * 4 + r] = acc[i][j][r];
          }
    }
#pragma unroll
    for (int i = 0; i < 2; ++i)
#pragma unroll
      for (int j = 0; j < 8; ++j)
#pragma unroll
        for (int r = 0; r < 4; ++r)
          sums[i * 4 + r] += EXP2F(acc[i][j][r]);
  }

#pragma unroll
  for (int tix = 0; tix < 8; ++tix) {
    float s = sums[tix];
    s += __shfl_xor(s, 1);
    s += __shfl_xor(s, 2);
    s += __shfl_xor(s, 4);
    s += __shfl_xor(s, 8);
    if (c16 == 0) {
      int i = tix >> 2, r = tix & 3;
      lseL[wm + i * 16 + quad * 4 + r] = LOG2F(s);
    }
  }

  // ---- fused V scale: t = 2^(diag - lse) * V for this block's 128 rows ----
  __syncthreads();                       // diagL/lseL visible
  const int row = tid >> 1, ch = tid & 1;
  const float w = EXP2F(diagL[row] - lseL[row]);
  const size_t grow = (size_t)(b * 2048 + m0 + row);
  const bf16* vsrc = qkv + grow * NQKV + 4096 + h * 128 + ch * 64;
  bf16* tdst = t + grow * 2048 + h * 128 + ch * 64;
#pragma unroll
  for (int c = 0; c < 8; ++c) {
    bf16x8 vv = *(const bf16x8*)(vsrc + c * 8);
    bf16x8 oo;
#pragma unroll
    for (int r = 0; r < 8; ++r) oo[r] = (bf16)((float)vv[r] * w);
    *(bf16x8*)(tdst + c * 8) = oo;
  }
}

// ---------------------------------------------------------------------------
// GEMM2: out(f32) = t(4096x2048 bf16) * Wo^T(2048x2048 bf16). BK=64, packed
// f32x2 stores via lane-pair shfl. (round-0 verified structure; UNCHANGED —
// grid-limited to 2 blocks/CU, so BK=32 would only double barrier count)
__global__ __launch_bounds__(256, 2) void gemm_out(
    const bf16* __restrict__ A, const bf16* __restrict__ Bm, float* __restrict__ C) {
  __shared__ alignas(16) bf16 As[2][128 * 32];
  __shared__ alignas(16) bf16 Bs[2][128 * 32];
  const int tid = threadIdx.x;
  const int lane = tid & 63, wv = tid >> 6;
  const int quad = lane >> 4, c16 = lane & 15;
  const int wm = (wv >> 1) * 64, wn = (wv & 1) * 64;
  const int m0 = blockIdx.y * 128, n0 = blockIdx.x * 128;

  const bf16* ag = A  + (size_t)(m0 + (tid >> 2)) * D_ + (tid & 3) * 8;
  const bf16* bg = Bm + (size_t)(n0 + (tid >> 2)) * D_ + (tid & 3) * 8;
  char* asl = (char*)As + tid * 16;
  char* bsl = (char*)Bs + tid * 16;

  f32x4 acc[4][4] = {};
  for (int k0 = 0; k0 < D_; k0 += 64) {
    __syncthreads();
    async16(ag + k0,                 asl);
    async16(ag + k0 + 64 * D_,       asl + 4096);
    async16(ag + k0 + 32,            asl + 8192);
    async16(ag + k0 + 32 + 64 * D_,  asl + 12288);
    async16(bg + k0,                 bsl);
    async16(bg + k0 + 64 * D_,       bsl + 4096);
    async16(bg + k0 + 32,            bsl + 8192);
    async16(bg + k0 + 32 + 64 * D_,  bsl + 12288);
    __syncthreads();
#pragma unroll
    for (int half = 0; half < 2; ++half) {
      bf16x8 af[4], bfr[4];
#pragma unroll
      for (int i = 0; i < 4; ++i)
        af[i] = *(const bf16x8*)(As[half] + (wm + i * 16 + c16) * 32 + quad * 8);
#pragma unroll
      for (int j = 0; j < 4; ++j)
        bfr[j] = *(const bf16x8*)(Bs[half] + (wn + j * 16 + c16) * 32 + quad * 8);
#pragma unroll
      for (int i = 0; i < 4; ++i)
#pragma unroll
        for (int j = 0; j < 4; ++j)
          acc[i][j] = __builtin_amdgcn_mfma_f32_16x16x32_bf16(af[i], bfr[j], acc[i][j], 0, 0, 0);
    }
  }
#pragma unroll
  for (int i = 0; i < 4; ++i)
#pragma unroll
    for (int j = 0; j < 4; ++j)
#pragma unroll
      for (int r = 0; r < 4; ++r) {
        float v = acc[i][j][r];
        float p = __shfl_xor(v, 1);
        if (!(lane & 1)) {
          int gm = m0 + wm + i * 16 + quad * 4 + r;
          int gn = n0 + wn + j * 16 + c16;
          float2 o = {v, p};
          *(float2*)(C + (size_t)gm * D_ + gn) = o;
        }
      }
}

// ---------------------------------------------------------------------------
extern "C" void kernel_launch(void* const* d_in, const int* in_sizes, int n_in,
                              void* d_out, int out_size, void* d_ws, size_t ws_size,
                              hipStream_t stream) {
  (void)in_sizes; (void)n_in; (void)out_size; (void)ws_size;
  const float* x  = (const float*)d_in[0];
  const float* rc = (const float*)d_in[1];
  const float* rs = (const float*)d_in[2];
  const float* Wq = (const float*)d_in[3];
  const float* Wk = (const float*)d_in[4];
  const float* Wv = (const float*)d_in[5];
  const float* Wo = (const float*)d_in[6];

  char* ws = (char*)d_ws;
  bf16* xb   = (bf16*)ws;                          // 16 MB slot (x bf16; reused as t)
  bf16* wqkv = (bf16*)(ws + 16777216);             // 24 MB (6144x2048)
  bf16* wob  = (bf16*)(ws + 16777216 + 25165824);  // 8 MB
  bf16* qkv  = (bf16*)(ws + 16777216 + 25165824 + 8388608);   // 48 MB (4096x6144)

  cvt_all<<<24576, 256, 0, stream>>>(x, Wq, Wk, Wv, Wo, xb, wqkv, wob);
  gemm_qkv<<<dim3(48, 32), 256, 0, stream>>>(xb, wqkv, rc, rs, qkv);
  score_wv<<<dim3(16, 32), 256, 0, stream>>>(qkv, xb /* t reuses xb */);
  gemm_out<<<dim3(16, 32), 256, 0, stream>>>(xb, wob, (float*)d_out);
}

// Round 6
// 363.218 us; speedup vs baseline: 1.0639x; 1.0639x over previous
//
#include <hip/hip_runtime.h>

// Problem constants: B=2, S=2048, D=2048, H=16, DH=128
#define B_  2
#define S_  2048
#define D_  2048
#define H_  16
#define DH_ 128
#define NQKV 6144              // Q|K|V concatenated column dim

typedef __bf16 bf16;
typedef __bf16 bf16x2 __attribute__((ext_vector_type(2)));
typedef __bf16 bf16x4 __attribute__((ext_vector_type(4)));
typedef __bf16 bf16x8 __attribute__((ext_vector_type(8)));
typedef float  f32x4  __attribute__((ext_vector_type(4)));

// 2^x and log2(x) via the raw ISA ops (v_exp_f32 / v_log_f32).
#define EXP2F(x) __builtin_amdgcn_exp2f(x)
#define LOG2F(x) __builtin_amdgcn_logf(x)

// DH^-0.5 * log2(e): fold softmax scale AND the exp->exp2 conversion into Q.
static constexpr float kQScale = 0.08838834764831845f * 1.4426950408889634f;

__device__ __forceinline__ void async16(const void* g, void* l) {
  __builtin_amdgcn_global_load_lds(
      (const __attribute__((address_space(1))) void*)g,
      (__attribute__((address_space(3))) void*)l, 16, 0, 0);
}

// ---------------------------------------------------------------------------
// Single fp32 -> bf16 conversion kernel for all 5 tensors (block-uniform
// region select; merging 5 dispatches -> 1 to cut launch overhead).
// Regions (blocks of 1024 elems): x:8192 | Wq:4096 | Wk:4096 | Wv:4096 | Wo:4096
__global__ void cvt_all(const float* __restrict__ x,  const float* __restrict__ wq,
                        const float* __restrict__ wk, const float* __restrict__ wv,
                        const float* __restrict__ wo,
                        bf16* __restrict__ xb, bf16* __restrict__ wqkv,
                        bf16* __restrict__ wob) {
  int bid = blockIdx.x;
  const float* s; bf16* d; int base;
  if (bid < 8192)        { s = x;  d = xb;             base = bid; }
  else if (bid < 12288)  { s = wq; d = wqkv;           base = bid - 8192; }
  else if (bid < 16384)  { s = wk; d = wqkv + 4194304; base = bid - 12288; }
  else if (bid < 20480)  { s = wv; d = wqkv + 8388608; base = bid - 16384; }
  else                   { s = wo; d = wob;            base = bid - 20480; }
  int i = (base * 256 + threadIdx.x) * 4;
  float4 v = *(const float4*)(s + i);
  bf16x4 o = {(bf16)v.x, (bf16)v.y, (bf16)v.z, (bf16)v.w};
  *(bf16x4*)(d + i) = o;
}

// ---------------------------------------------------------------------------
// GEMM1 (round-0 FROZEN form, 141.8 us measured): qkv = x(4096x2048) *
// Wqkv^T (6144x2048), RoPE fused for the Q,K column regions (f32 via lane-pair
// shfl), Q scaled by kQScale. Output row-major 4096x6144 bf16. BK=64 (two 32-K
// sub-tiles per barrier pair). Schedule history: 8-phase/256^2 r2=187us,
// r3=223us; BK=32 r5=175us — ALL regressed vs this. Do not touch the schedule.
__global__ __launch_bounds__(256, 2) void gemm_qkv(
    const bf16* __restrict__ A, const bf16* __restrict__ Bm,
    const float* __restrict__ rc, const float* __restrict__ rs,
    bf16* __restrict__ C) {
  __shared__ alignas(16) bf16 As[2][128 * 32];   // 16 KB
  __shared__ alignas(16) bf16 Bs[2][128 * 32];   // 16 KB
  const int tid = threadIdx.x;
  const int lane = tid & 63;
  const int wv = tid >> 6;
  const int quad = lane >> 4, c16 = lane & 15;
  const int wm = (wv >> 1) * 64, wn = (wv & 1) * 64;
  const int m0 = blockIdx.y * 128, n0 = blockIdx.x * 128;

  const bf16* ag = A  + (size_t)(m0 + (tid >> 2)) * D_ + (tid & 3) * 8;
  const bf16* bg = Bm + (size_t)(n0 + (tid >> 2)) * D_ + (tid & 3) * 8;
  char* asl = (char*)As + tid * 16;
  char* bsl = (char*)Bs + tid * 16;

  f32x4 acc[4][4] = {};
  for (int k0 = 0; k0 < D_; k0 += 64) {
    __syncthreads();
    async16(ag + k0,                 asl);
    async16(ag + k0 + 64 * D_,       asl + 4096);
    async16(ag + k0 + 32,            asl + 8192);
    async16(ag + k0 + 32 + 64 * D_,  asl + 12288);
    async16(bg + k0,                 bsl);
    async16(bg + k0 + 64 * D_,       bsl + 4096);
    async16(bg + k0 + 32,            bsl + 8192);
    async16(bg + k0 + 32 + 64 * D_,  bsl + 12288);
    __syncthreads();
#pragma unroll
    for (int half = 0; half < 2; ++half) {
      bf16x8 af[4], bfr[4];
#pragma unroll
      for (int i = 0; i < 4; ++i)
        af[i] = *(const bf16x8*)(As[half] + (wm + i * 16 + c16) * 32 + quad * 8);
#pragma unroll
      for (int j = 0; j < 4; ++j)
        bfr[j] = *(const bf16x8*)(Bs[half] + (wn + j * 16 + c16) * 32 + quad * 8);
#pragma unroll
      for (int i = 0; i < 4; ++i)
#pragma unroll
        for (int j = 0; j < 4; ++j)
          acc[i][j] = __builtin_amdgcn_mfma_f32_16x16x32_bf16(af[i], bfr[j], acc[i][j], 0, 0, 0);
    }
  }

  // ---- epilogue (n0 block-uniform: Q / K get RoPE, V passes through) ----
  if (n0 < 4096) {
    const float sc = (n0 < 2048) ? kQScale : 1.0f;
#pragma unroll
    for (int i = 0; i < 4; ++i) {
      const int gmi = m0 + wm + i * 16 + quad * 4;
#pragma unroll
      for (int j = 0; j < 4; ++j) {
        const int gn = n0 + wn + j * 16 + c16;
        const int d = gn & 127;
#pragma unroll
        for (int r = 0; r < 4; ++r) {
          float v = acc[i][j][r];
          float p = __shfl_xor(v, 1);          // partner (odd<->even d)
          const int gm = gmi + r;
          const int s = gm & 2047;
          const int si = s * 64 + (d >> 1);
          float c = rc[si], sn = rs[si];
          float re = (v * c - p * sn) * sc;    // valid on even lanes
          float im = (v * sn + p * c) * sc;
          if (!(lane & 1)) {
            bf16x2 o = {(bf16)re, (bf16)im};
            *(bf16x2*)(C + (size_t)gm * NQKV + gn) = o;
          }
        }
      }
    }
  } else {
#pragma unroll
    for (int i = 0; i < 4; ++i) {
      const int gmi = m0 + wm + i * 16 + quad * 4;
#pragma unroll
      for (int j = 0; j < 4; ++j) {
        const int gn = n0 + wn + j * 16 + c16;
#pragma unroll
        for (int r = 0; r < 4; ++r) {
          float v = acc[i][j][r];
          float p = __shfl_xor(v, 1);
          if (!(lane & 1)) {
            bf16x2 o = {(bf16)v, (bf16)p};
            *(bf16x2*)(C + (size_t)(gmi + r) * NQKV + gn) = o;
          }
        }
      }
    }
  }
}

// ---------------------------------------------------------------------------
// Fused per-(b,h) score + weight + V-scale kernel (v4 = v3 + K prefetch):
//   lse2[s] = log2 sum_k 2^(q'_s . k_k), diag2[s] = q'_s . k_s  (LDS only)
//   t[b,s,h*128+d] = 2^(diag2-lse2) * V[b,s,h*128+d]
// v3 (kept, measured ~21us win vs v1): Q-hoist to VGPR (no Qs LDS); K tile
// [128][128] 256-B rows XOR-swizzled (chunk ^= row&7), conflict-free reads.
// v4 (this round): DOUBLE-BUFFERED K with counted vmcnt — issue next tile's
// 8 global_load_lds at iter top, s_waitcnt vmcnt(8) (waits PREVIOUS tile's 8,
// the new 8 stay in flight across the raw s_barrier), compute, bottom barrier.
// Barrier count unchanged (2/iter); staging latency now hidden under one full
// compute phase. Last iter: vmcnt(0) (vmcnt(8) with exactly 8 outstanding
// would not wait at all). Bottom barrier separates stage(it)'s writes to
// buf[(it&1)^1] from iter-(it-1)'s readers of that same buffer.
__global__ __launch_bounds__(256, 2) void score_wv(
    const bf16* __restrict__ qkv, bf16* __restrict__ t) {
  __shared__ alignas(16) bf16 Ks[2 * 128 * 128];  // 64 KB, 2 swizzled buffers
  __shared__ float diagL[128];
  __shared__ float lseL[128];
  const int tid = threadIdx.x;
  const int lane = tid & 63, wv = tid >> 6;
  const int quad = lane >> 4, c16 = lane & 15;
  const int wm = wv * 32;                 // each wave owns 32 distinct Q rows
  const int bh = blockIdx.y;
  const int b = bh >> 4, h = bh & 15;
  const int m0 = blockIdx.x * 128;

  // ---- Q-hoist: fragments direct global->VGPR (32 VGPRs), once ----
  bf16x8 qf[2][4];                        // [i][kt]
  {
    const bf16* qbase = qkv + (size_t)(b * 2048 + m0 + wm + c16) * NQKV
                      + h * 128 + quad * 8;
#pragma unroll
    for (int i = 0; i < 2; ++i)
#pragma unroll
      for (int kt = 0; kt < 4; ++kt)
        qf[i][kt] = *(const bf16x8*)(qbase + (size_t)(i * 16) * NQKV + kt * 32);
  }

  // ---- K staging map: thread tid -> row i*16+(tid>>4), chunk tid&15 (linear
  //      dest tid*16 + i*4096); source chunk pre-swizzled by row&7 ----
  const int srow = tid >> 4;                    // 0..15
  const int schunk = (tid & 15) ^ (srow & 7);   // involution partner
  const bf16* kg = qkv + (size_t)(b * 2048 + srow) * NQKV
                 + 2048 + h * 128 + schunk * 8;
  char* kl = (char*)Ks + tid * 16;

  float sums[8] = {0.f, 0.f, 0.f, 0.f, 0.f, 0.f, 0.f, 0.f};

  // ---- prologue: stage tile 0 into buf 0 ----
#pragma unroll
  for (int i = 0; i < 8; ++i)
    async16(kg + (size_t)(i * 16) * NQKV, kl + i * 4096);

  for (int it = 0; it < 16; ++it) {
    const int n0 = it * 128;
    // issue next tile into the other buffer, then counted wait on current
    if (it < 15) {
      char* klN = kl + (((it & 1) ^ 1) << 15);
#pragma unroll
      for (int i = 0; i < 8; ++i)
        async16(kg + (size_t)(n0 + 128 + i * 16) * NQKV, klN + i * 4096);
      asm volatile("s_waitcnt vmcnt(8)" ::: "memory");
    } else {
      asm volatile("s_waitcnt vmcnt(0)" ::: "memory");
    }
    __builtin_amdgcn_s_barrier();               // current buffer landed chip-wide

    const char* kb = (const char*)Ks + ((it & 1) << 15);
    f32x4 acc[2][8] = {};
#pragma unroll
    for (int kt = 0; kt < 4; ++kt) {
#pragma unroll
      for (int j = 0; j < 8; ++j) {
        // row j*16+c16, chunk (kt*4+quad) ^ (c16&7)  [row&7 == c16&7]
        bf16x8 bb = *(const bf16x8*)(kb + (j * 16 + c16) * 256
                        + ((((kt * 4 + quad) ^ (c16 & 7))) << 4));
#pragma unroll
        for (int i = 0; i < 2; ++i)
          acc[i][j] = __builtin_amdgcn_mfma_f32_16x16x32_bf16(qf[i][kt], bb, acc[i][j], 0, 0, 0);
      }
    }
    // Diagonal tile only; compile-time acc indices, wave-uniform j guard.
    if (n0 == m0) {
#pragma unroll
      for (int i = 0; i < 2; ++i)
#pragma unroll
        for (int j = 0; j < 8; ++j)
          if (j == 2 * wv + i) {
#pragma unroll
            for (int r = 0; r < 4; ++r)
              if (c16 == quad * 4 + r)
                diagL[wm + i * 16 + quad * 4 + r] = acc[i][j][r];
          }
    }
#pragma unroll
    for (int i = 0; i < 2; ++i)
#pragma unroll
      for (int j = 0; j < 8; ++j)
#pragma unroll
        for (int r = 0; r < 4; ++r)
          sums[i * 4 + r] += EXP2F(acc[i][j][r]);

    __builtin_amdgcn_s_barrier();               // readers done before next stage
  }

#pragma unroll
  for (int tix = 0; tix < 8; ++tix) {
    float s = sums[tix];
    s += __shfl_xor(s, 1);
    s += __shfl_xor(s, 2);
    s += __shfl_xor(s, 4);
    s += __shfl_xor(s, 8);
    if (c16 == 0) {
      int i = tix >> 2, r = tix & 3;
      lseL[wm + i * 16 + quad * 4 + r] = LOG2F(s);
    }
  }

  // ---- fused V scale: t = 2^(diag - lse) * V for this block's 128 rows ----
  __syncthreads();                       // diagL/lseL visible
  const int row = tid >> 1, ch = tid & 1;
  const float w = EXP2F(diagL[row] - lseL[row]);
  const size_t grow = (size_t)(b * 2048 + m0 + row);
  const bf16* vsrc = qkv + grow * NQKV + 4096 + h * 128 + ch * 64;
  bf16* tdst = t + grow * 2048 + h * 128 + ch * 64;
#pragma unroll
  for (int c = 0; c < 8; ++c) {
    bf16x8 vv = *(const bf16x8*)(vsrc + c * 8);
    bf16x8 oo;
#pragma unroll
    for (int r = 0; r < 8; ++r) oo[r] = (bf16)((float)vv[r] * w);
    *(bf16x8*)(tdst + c * 8) = oo;
  }
}

// ---------------------------------------------------------------------------
// GEMM2: out(f32) = t(4096x2048 bf16) * Wo^T(2048x2048 bf16). BK=64, packed
// f32x2 stores via lane-pair shfl. (round-0 verified structure; UNCHANGED)
__global__ __launch_bounds__(256, 2) void gemm_out(
    const bf16* __restrict__ A, const bf16* __restrict__ Bm, float* __restrict__ C) {
  __shared__ alignas(16) bf16 As[2][128 * 32];
  __shared__ alignas(16) bf16 Bs[2][128 * 32];
  const int tid = threadIdx.x;
  const int lane = tid & 63, wv = tid >> 6;
  const int quad = lane >> 4, c16 = lane & 15;
  const int wm = (wv >> 1) * 64, wn = (wv & 1) * 64;
  const int m0 = blockIdx.y * 128, n0 = blockIdx.x * 128;

  const bf16* ag = A  + (size_t)(m0 + (tid >> 2)) * D_ + (tid & 3) * 8;
  const bf16* bg = Bm + (size_t)(n0 + (tid >> 2)) * D_ + (tid & 3) * 8;
  char* asl = (char*)As + tid * 16;
  char* bsl = (char*)Bs + tid * 16;

  f32x4 acc[4][4] = {};
  for (int k0 = 0; k0 < D_; k0 += 64) {
    __syncthreads();
    async16(ag + k0,                 asl);
    async16(ag + k0 + 64 * D_,       asl + 4096);
    async16(ag + k0 + 32,            asl + 8192);
    async16(ag + k0 + 32 + 64 * D_,  asl + 12288);
    async16(bg + k0,                 bsl);
    async16(bg + k0 + 64 * D_,       bsl + 4096);
    async16(bg + k0 + 32,            bsl + 8192);
    async16(bg + k0 + 32 + 64 * D_,  bsl + 12288);
    __syncthreads();
#pragma unroll
    for (int half = 0; half < 2; ++half) {
      bf16x8 af[4], bfr[4];
#pragma unroll
      for (int i = 0; i < 4; ++i)
        af[i] = *(const bf16x8*)(As[half] + (wm + i * 16 + c16) * 32 + quad * 8);
#pragma unroll
      for (int j = 0; j < 4; ++j)
        bfr[j] = *(const bf16x8*)(Bs[half] + (wn + j * 16 + c16) * 32 + quad * 8);
#pragma unroll
      for (int i = 0; i < 4; ++i)
#pragma unroll
        for (int j = 0; j < 4; ++j)
          acc[i][j] = __builtin_amdgcn_mfma_f32_16x16x32_bf16(af[i], bfr[j], acc[i][j], 0, 0, 0);
    }
  }
#pragma unroll
  for (int i = 0; i < 4; ++i)
#pragma unroll
    for (int j = 0; j < 4; ++j)
#pragma unroll
      for (int r = 0; r < 4; ++r) {
        float v = acc[i][j][r];
        float p = __shfl_xor(v, 1);
        if (!(lane & 1)) {
          int gm = m0 + wm + i * 16 + quad * 4 + r;
          int gn = n0 + wn + j * 16 + c16;
          float2 o = {v, p};
          *(float2*)(C + (size_t)gm * D_ + gn) = o;
        }
      }
}

// ---------------------------------------------------------------------------
extern "C" void kernel_launch(void* const* d_in, const int* in_sizes, int n_in,
                              void* d_out, int out_size, void* d_ws, size_t ws_size,
                              hipStream_t stream) {
  (void)in_sizes; (void)n_in; (void)out_size; (void)ws_size;
  const float* x  = (const float*)d_in[0];
  const float* rc = (const float*)d_in[1];
  const float* rs = (const float*)d_in[2];
  const float* Wq = (const float*)d_in[3];
  const float* Wk = (const float*)d_in[4];
  const float* Wv = (const float*)d_in[5];
  const float* Wo = (const float*)d_in[6];

  char* ws = (char*)d_ws;
  bf16* xb   = (bf16*)ws;                          // 16 MB slot (x bf16; reused as t)
  bf16* wqkv = (bf16*)(ws + 16777216);             // 24 MB (6144x2048)
  bf16* wob  = (bf16*)(ws + 16777216 + 25165824);  // 8 MB
  bf16* qkv  = (bf16*)(ws + 16777216 + 25165824 + 8388608);   // 48 MB (4096x6144)

  cvt_all<<<24576, 256, 0, stream>>>(x, Wq, Wk, Wv, Wo, xb, wqkv, wob);
  gemm_qkv<<<dim3(48, 32), 256, 0, stream>>>(xb, wqkv, rc, rs, qkv);
  score_wv<<<dim3(16, 32), 256, 0, stream>>>(qkv, xb /* t reuses xb */);
  gemm_out<<<dim3(16, 32), 256, 0, stream>>>(xb, wob, (float*)d_out);
}